// Round 2
// baseline (3136.348 us; speedup 1.0000x reference)
//
#include <hip/hip_runtime.h>
#include <math.h>

#define DEV static __device__ __forceinline__

// ---------------- helpers ----------------
DEV float wsum(float v){
#pragma unroll
  for(int m=32;m>=1;m>>=1) v += __shfl_xor(v, m);
  return v;
}
DEV float gelu_f(float v){
  return 0.5f*v*(1.0f + erff(v*0.70710678118654752440f));
}

// ---------------- k_ft_sq: f = w_it@x + b_it (stored transposed ft[b][n][c]), sq = sum(x^2) ----------------
__global__ __launch_bounds__(256) void k_ft_sq(
    const float* __restrict__ x, const float* __restrict__ w_it,
    const float* __restrict__ b_it, float* __restrict__ ft, float* __restrict__ sq)
{
  int g = blockIdx.x*256 + threadIdx.x;      // 8192 = B*N
  int b = g >> 11, n = g & 2047;
  const float* xb = x + (size_t)b*6144;
  float x0 = xb[n], x1v = xb[2048+n], x2 = xb[4096+n];
  sq[g] = x0*x0 + x1v*x1v + x2*x2;
  float* o = ft + (size_t)g*32;
#pragma unroll
  for(int c=0;c<32;c++)
    o[c] = w_it[c*3]*x0 + w_it[c*3+1]*x1v + w_it[c*3+2]*x2 + b_it[c];
}

// ---------------- k_knn: top-16 nearest (incl self), top_k tie semantics ----------------
__global__ __launch_bounds__(256) void k_knn(
    const float* __restrict__ x, const float* __restrict__ sq, int* __restrict__ knnidx)
{
  __shared__ float dbuf[4][2048];
  int w = threadIdx.x >> 6, l = threadIdx.x & 63;
  int row = blockIdx.x*4 + w;                // b*2048+n
  int b = row >> 11, n = row & 2047;
  const float* xb = x + (size_t)b*6144;
  const float* sqb = sq + (size_t)b*2048;
  float px = xb[n], py = xb[2048+n], pz = xb[4096+n], sqi = sqb[n];
  for(int j = l; j < 2048; j += 64){
    float dot = xb[j]*px + xb[2048+j]*py + xb[4096+j]*pz;
    dbuf[w][j] = sqi - 2.0f*dot + sqb[j];
  }
  __syncthreads();
  const float INFV = 3.0e38f;
  int* orow = knnidx + (size_t)row*16;
  int base = l*32;
  for(int r=0;r<16;r++){
    float best = INFV; int bi = 0;
#pragma unroll
    for(int u=0;u<8;u++){
      float4 v = *(const float4*)&dbuf[w][base + u*4];
      int j0 = base + u*4;
      if(v.x < best){best=v.x; bi=j0;}
      if(v.y < best){best=v.y; bi=j0+1;}
      if(v.z < best){best=v.z; bi=j0+2;}
      if(v.w < best){best=v.w; bi=j0+3;}
    }
#pragma unroll
    for(int m=1;m<64;m<<=1){
      float ov = __shfl_xor(best, m); int oi = __shfl_xor(bi, m);
      if(ov < best || (ov == best && oi < bi)){ best = ov; bi = oi; }
    }
    if(l==0){ orow[r] = bi; dbuf[w][bi] = INFV; }
    __syncthreads();
  }
}

// ---------------- k_ln: LayerNorm over last dim 2048 ----------------
__global__ __launch_bounds__(256) void k_ln(const float* __restrict__ in,
    const float* __restrict__ g, const float* __restrict__ bb, float* __restrict__ out)
{
  int row = blockIdx.x, t = threadIdx.x;
  const float4* in4 = (const float4*)(in + (size_t)row*2048);
  float4 a = in4[t], c = in4[t+256];
  float sm = a.x+a.y+a.z+a.w + c.x+c.y+c.z+c.w;
  float ssq = a.x*a.x+a.y*a.y+a.z*a.z+a.w*a.w + c.x*c.x+c.y*c.y+c.z*c.z+c.w*c.w;
  sm = wsum(sm); ssq = wsum(ssq);
  __shared__ float sh[8];
  int w = t>>6, l = t&63;
  if(l==0){ sh[w] = sm; sh[4+w] = ssq; }
  __syncthreads();
  sm = sh[0]+sh[1]+sh[2]+sh[3];
  ssq = sh[4]+sh[5]+sh[6]+sh[7];
  float mean = sm * (1.f/2048.f);
  float rs = rsqrtf(ssq*(1.f/2048.f) - mean*mean + 1e-5f);
  const float4* g4 = (const float4*)g; const float4* b4 = (const float4*)bb;
  float4* o4 = (float4*)(out + (size_t)row*2048);
  float4 g0 = g4[t], b0 = b4[t], g1 = g4[t+256], b1 = b4[t+256];
  float4 r0, r1;
  r0.x=(a.x-mean)*rs*g0.x+b0.x; r0.y=(a.y-mean)*rs*g0.y+b0.y;
  r0.z=(a.z-mean)*rs*g0.z+b0.z; r0.w=(a.w-mean)*rs*g0.w+b0.w;
  r1.x=(c.x-mean)*rs*g1.x+b1.x; r1.y=(c.y-mean)*rs*g1.y+b1.y;
  r1.z=(c.z-mean)*rs*g1.z+b1.z; r1.w=(c.w-mean)*rs*g1.w+b1.w;
  o4[t] = r0; o4[t+256] = r1;
}

// ---------------- k_qkv1: qkv1 = nx @ W^T (12 rows), wave per W-row ----------------
__global__ __launch_bounds__(256) void k_qkv1(
    const float* __restrict__ nx, const float* __restrict__ W, float* __restrict__ outq)
{
  int w = threadIdx.x>>6, l = threadIdx.x&63;
  int c = blockIdx.x*4 + w;                  // 6144
  const float4* wrow = (const float4*)(W + (size_t)c*2048);
  float acc[12];
#pragma unroll
  for(int r=0;r<12;r++) acc[r]=0.f;
  for(int it=0; it<8; it++){
    int k4 = it*64 + l;
    float4 wv = wrow[k4];
#pragma unroll
    for(int r=0;r<12;r++){
      float4 a = ((const float4*)(nx + (size_t)r*2048))[k4];
      acc[r] += a.x*wv.x + a.y*wv.y + a.z*wv.z + a.w*wv.w;
    }
  }
#pragma unroll
  for(int r=0;r<12;r++) acc[r] = wsum(acc[r]);
  if(l==0){
#pragma unroll
    for(int r=0;r<12;r++) outq[(size_t)r*6144 + c] = acc[r];
  }
}

// ---------------- k_attn1: tiny attention over seq len 3 ----------------
__global__ __launch_bounds__(256) void k_attn1(const float* __restrict__ qkv1, float* __restrict__ obuf)
{
  int b = blockIdx.x >> 3, h = blockIdx.x & 7;
  __shared__ float s[3][3], p[3][3];
  int t = threadIdx.x; int w = t>>6, l = t&63;
  for(int dot = w; dot < 9; dot += 4){
    int n = dot/3, m = dot - n*3;
    const float* q = qkv1 + (size_t)(b*3+n)*6144 + h*256;
    const float* k = qkv1 + (size_t)(b*3+m)*6144 + 2048 + h*256;
    float4 qv = ((const float4*)q)[l];
    float4 kv = ((const float4*)k)[l];
    float a = qv.x*kv.x + qv.y*kv.y + qv.z*kv.z + qv.w*kv.w;
    a = wsum(a);
    if(l==0) s[n][m] = a * 0.0625f;
  }
  __syncthreads();
  if(t < 3){
    float m0 = fmaxf(s[t][0], fmaxf(s[t][1], s[t][2]));
    float e0 = expf(s[t][0]-m0), e1 = expf(s[t][1]-m0), e2 = expf(s[t][2]-m0);
    float inv = 1.f/(e0+e1+e2);
    p[t][0]=e0*inv; p[t][1]=e1*inv; p[t][2]=e2*inv;
  }
  __syncthreads();
  for(int i=t; i<768; i+=256){
    int n = i>>8, d = i&255;
    float o = 0.f;
#pragma unroll
    for(int m=0;m<3;m++) o += p[n][m] * qkv1[(size_t)(b*3+m)*6144 + 4096 + h*256 + d];
    obuf[(size_t)(b*3+n)*2048 + h*256 + d] = o;
  }
}

// ---------------- k_proj1: x1 = (nx - o) @ pw^T + pb, wave per W-row ----------------
__global__ __launch_bounds__(256) void k_proj1(
    const float* __restrict__ nx, const float* __restrict__ ob,
    const float* __restrict__ W, const float* __restrict__ bias, float* __restrict__ x1)
{
  int w = threadIdx.x>>6, l = threadIdx.x&63;
  int c = blockIdx.x*4 + w;                  // 2048
  const float4* wrow = (const float4*)(W + (size_t)c*2048);
  float acc[12];
#pragma unroll
  for(int r=0;r<12;r++) acc[r]=0.f;
  for(int it=0; it<8; it++){
    int k4 = it*64 + l;
    float4 wv = wrow[k4];
#pragma unroll
    for(int r=0;r<12;r++){
      float4 a = ((const float4*)(nx + (size_t)r*2048))[k4];
      float4 o = ((const float4*)(ob + (size_t)r*2048))[k4];
      acc[r] += (a.x-o.x)*wv.x + (a.y-o.y)*wv.y + (a.z-o.z)*wv.z + (a.w-o.w)*wv.w;
    }
  }
#pragma unroll
  for(int r=0;r<12;r++) acc[r] = wsum(acc[r]);
  if(l==0){
#pragma unroll
    for(int r=0;r<12;r++) x1[(size_t)r*2048 + c] = acc[r] + bias[c];
  }
}

// ---------------- fused graph-conv: conv1(+stats) / conv1->gn1->leaky->conv2->stats2+maxmin ----------------
template<int FULL>
__global__ __launch_bounds__(256) void k_convknn(
    const float* __restrict__ ft, const int* __restrict__ knnidx,
    const float* __restrict__ wl1, const float* __restrict__ wl2,
    const float* __restrict__ s1, const float* __restrict__ t1,
    float* __restrict__ part1, float* __restrict__ part2,
    float* __restrict__ hmax, float* __restrict__ hmin)
{
  __shared__ float smem[19712];
  float* gfT = smem;              // [64][36]
  float* w1t = smem + 2304;       // [64][260]
  float* a1T = smem;              // [256][36] (phase2 alias)
  float* w2t = smem + 9216;       // [64][132]
  float* mmb = smem + 17664;      // 2048

  int t = threadIdx.x;
  int posBase = blockIdx.x * 32;
  int b = posBase >> 15;

#pragma unroll
  for(int r=0;r<2;r++){
    int it = t + r*256;
    int pos = it & 31, cq = it >> 5;
    int s = posBase + pos;
    int n = (s >> 4) & 2047;
    float4 v;
    if(cq < 8){
      int j = knnidx[s];
      float4 aj = *(const float4*)&ft[((size_t)(b*2048 + j))*32 + cq*4];
      float4 an = *(const float4*)&ft[((size_t)(b*2048 + n))*32 + cq*4];
      v = make_float4(aj.x-an.x, aj.y-an.y, aj.z-an.z, aj.w-an.w);
    } else {
      v = *(const float4*)&ft[((size_t)(b*2048 + n))*32 + (cq-8)*4];
    }
    int c0 = cq*4;
    gfT[(c0+0)*36 + pos] = v.x;
    gfT[(c0+1)*36 + pos] = v.y;
    gfT[(c0+2)*36 + pos] = v.z;
    gfT[(c0+3)*36 + pos] = v.w;
  }
#pragma unroll
  for(int r=0;r<16;r++){
    int it = t + r*256;
    int ch = it & 255, kq = it >> 8;
    float4 v = *(const float4*)&wl1[(size_t)ch*64 + kq*4];
    w1t[(kq*4+0)*260 + ch] = v.x;
    w1t[(kq*4+1)*260 + ch] = v.y;
    w1t[(kq*4+2)*260 + ch] = v.z;
    w1t[(kq*4+3)*260 + ch] = v.w;
  }
  __syncthreads();

  int pos0 = (t & 7)*4, ch0 = (t >> 3)*8;
  float acc[4][8] = {};
#pragma unroll 4
  for(int k=0;k<64;k++){
    float4 a = *(const float4*)&gfT[k*36 + pos0];
    float4 w0 = *(const float4*)&w1t[(size_t)k*260 + ch0];
    float4 w1v = *(const float4*)&w1t[(size_t)k*260 + ch0 + 4];
    float av[4] = {a.x,a.y,a.z,a.w};
    float wv[8] = {w0.x,w0.y,w0.z,w0.w,w1v.x,w1v.y,w1v.z,w1v.w};
#pragma unroll
    for(int p=0;p<4;p++)
#pragma unroll
      for(int c=0;c<8;c++) acc[p][c] += av[p]*wv[c];
  }
  if(!FULL){
    float sm=0.f, ssq=0.f;
#pragma unroll
    for(int p=0;p<4;p++)
#pragma unroll
      for(int c=0;c<8;c++){ float v = acc[p][c]; sm += v; ssq += v*v; }
    sm = wsum(sm); ssq = wsum(ssq);
    int w = t >> 6, l = t & 63;
    if(l==0){ part1[(size_t)blockIdx.x*8 + w*2] = sm; part1[(size_t)blockIdx.x*8 + w*2 + 1] = ssq; }
    return;
  }
  float sv[8], tv[8];
#pragma unroll
  for(int c=0;c<8;c++){ sv[c] = s1[b*256 + ch0 + c]; tv[c] = t1[b*256 + ch0 + c]; }
  __syncthreads();          // all GEMM1 LDS reads done before a1T overwrite
#pragma unroll
  for(int c=0;c<8;c++){
#pragma unroll
    for(int p=0;p<4;p++){
      float a = sv[c]*acc[p][c] + tv[c];
      a = a >= 0.f ? a : 0.2f*a;
      a1T[(size_t)(ch0+c)*36 + pos0 + p] = a;
    }
  }
  float acc2[4][4] = {};
  int oc0 = (t >> 3)*4;
  for(int cc=0; cc<4; cc++){
#pragma unroll
    for(int r=0;r<8;r++){
      int it = t + r*256;
      int ch = it & 127, kq = it >> 7;
      float4 v = *(const float4*)&wl2[(size_t)ch*256 + cc*64 + kq*4];
      w2t[(kq*4+0)*132 + ch] = v.x;
      w2t[(kq*4+1)*132 + ch] = v.y;
      w2t[(kq*4+2)*132 + ch] = v.z;
      w2t[(kq*4+3)*132 + ch] = v.w;
    }
    __syncthreads();
#pragma unroll 8
    for(int kk=0;kk<64;kk++){
      float4 a = *(const float4*)&a1T[(size_t)(cc*64+kk)*36 + pos0];
      float4 w = *(const float4*)&w2t[kk*132 + oc0];
      float av[4] = {a.x,a.y,a.z,a.w};
      float wv[4] = {w.x,w.y,w.z,w.w};
#pragma unroll
      for(int p=0;p<4;p++)
#pragma unroll
        for(int c=0;c<4;c++) acc2[p][c] += av[p]*wv[c];
    }
    __syncthreads();
  }
  {
    float sm=0.f, ssq=0.f;
#pragma unroll
    for(int p=0;p<4;p++)
#pragma unroll
      for(int c=0;c<4;c++){ float v = acc2[p][c]; sm += v; ssq += v*v; }
    sm = wsum(sm); ssq = wsum(ssq);
    int w = t >> 6, l = t & 63;
    if(l==0){ part2[(size_t)blockIdx.x*8 + w*2] = sm; part2[(size_t)blockIdx.x*8 + w*2 + 1] = ssq; }
  }
  float* maxb = mmb; float* minb = mmb + 1024;
  int nloc = pos0 >> 4, kg = (pos0 & 15) >> 2;
#pragma unroll
  for(int c=0;c<4;c++){
    float mx = fmaxf(fmaxf(acc2[0][c], acc2[1][c]), fmaxf(acc2[2][c], acc2[3][c]));
    float mn = fminf(fminf(acc2[0][c], acc2[1][c]), fminf(acc2[2][c], acc2[3][c]));
    maxb[(nloc*4 + kg)*128 + oc0 + c] = mx;
    minb[(nloc*4 + kg)*128 + oc0 + c] = mn;
  }
  __syncthreads();
  {
    int nl = t >> 7, c = t & 127;
    float mx = maxb[(nl*4+0)*128 + c];
    float mn = minb[(nl*4+0)*128 + c];
#pragma unroll
    for(int k2=1;k2<4;k2++){
      mx = fmaxf(mx, maxb[(nl*4+k2)*128 + c]);
      mn = fminf(mn, minb[(nl*4+k2)*128 + c]);
    }
    int n = ((posBase >> 4) & 2047) + nl;
    hmax[((size_t)(b*128 + c))*2048 + n] = mx;
    hmin[((size_t)(b*128 + c))*2048 + n] = mn;
  }
}

// ---------------- GN finalizers ----------------
__global__ __launch_bounds__(256) void k_gn1fin(const float* __restrict__ part,
    const float* __restrict__ g, const float* __restrict__ bb,
    float* __restrict__ s1, float* __restrict__ t1)
{
  __shared__ float sums[4][4][2];
  int t = threadIdx.x;
  if(t < 32){
    int b = t >> 3, gr = (t >> 1) & 3, wh = t & 1;
    float a = 0.f;
    for(int blk = b*1024; blk < (b+1)*1024; blk++) a += part[(size_t)blk*8 + gr*2 + wh];
    sums[b][gr][wh] = a;
  }
  __syncthreads();
  const float inv = 1.f/(64.f*32768.f);
  for(int i=t;i<1024;i+=256){
    int b = i >> 8, c = i & 255, gr = c >> 6;
    float mean = sums[b][gr][0]*inv;
    float var = sums[b][gr][1]*inv - mean*mean;
    float svv = g[c]*rsqrtf(var + 1e-5f);
    s1[b*256+c] = svv;
    t1[b*256+c] = bb[c] - mean*svv;
  }
}
__global__ __launch_bounds__(256) void k_gn2fin(const float* __restrict__ part,
    const float* __restrict__ g, const float* __restrict__ bb,
    float* __restrict__ s2, float* __restrict__ t2)
{
  __shared__ float sums[4][4][2];
  int t = threadIdx.x;
  if(t < 32){
    int b = t >> 3, gr = (t >> 1) & 3, wh = t & 1;
    float a = 0.f;
    for(int blk = b*1024; blk < (b+1)*1024; blk++) a += part[(size_t)blk*8 + gr*2 + wh];
    sums[b][gr][wh] = a;
  }
  __syncthreads();
  const float inv = 1.f/(32.f*32768.f);
  for(int i=t;i<512;i+=256){
    int b = i >> 7, c = i & 127, gr = c >> 5;
    float mean = sums[b][gr][0]*inv;
    float var = sums[b][gr][1]*inv - mean*mean;
    float svv = g[c]*rsqrtf(var + 1e-5f);
    s2[b*128+c] = svv;
    t2[b*128+c] = bb[c] - mean*svv;
  }
}

// ---------------- k_knnf: knn_f = leaky(gn2 applied to max/min) ----------------
__global__ __launch_bounds__(256) void k_knnf(const float* __restrict__ hmax,
    const float* __restrict__ hmin, const float* __restrict__ s2,
    const float* __restrict__ t2, float* __restrict__ knnf)
{
  int i = blockIdx.x*256 + threadIdx.x;       // 262144 float4 groups
  int bc = i >> 9;
  int b = bc >> 7, c = bc & 127;
  float s = s2[b*128+c], tt = t2[b*128+c];
  float4 mx = ((const float4*)hmax)[i], mn = ((const float4*)hmin)[i];
  float4 v = (s >= 0.f) ? mx : mn;
  float4 r;
  r.x = s*v.x + tt; r.y = s*v.y + tt; r.z = s*v.z + tt; r.w = s*v.w + tt;
  r.x = r.x >= 0.f ? r.x : 0.2f*r.x;
  r.y = r.y >= 0.f ? r.y : 0.2f*r.y;
  r.z = r.z >= 0.f ? r.z : 0.2f*r.z;
  r.w = r.w >= 0.f ? r.w : 0.2f*r.w;
  ((float4*)knnf)[i] = r;
}

// ---------------- generic tiled SGEMM-BT: C = epi(A @ W^T (+bias) (+resid)) ----------------
// ASRC: 0 direct (stride Kd) | 1 concat of A/A2 (each stride 2048)
// WSRC: 0 direct (W: N2 x Kd, K-contig) | 1 on-the-fly gelu(c1 @ x1) per batch z
// EPI:  0 none | 1 gelu | 2 +resid
template<int ASRC, int WSRC, int EPI>
__global__ __launch_bounds__(256) void k_gemm(
    const float* __restrict__ A, const float* __restrict__ A2,
    const float* __restrict__ Wm, const float* __restrict__ x1b_, const float* __restrict__ c1w,
    const float* __restrict__ bias, const float* __restrict__ resid,
    float* __restrict__ C, int M, int N2, int Kd)
{
  __shared__ float At[32*68], Wt[32*68];
  int t = threadIdx.x;
  int n0 = blockIdx.x*64, m0 = blockIdx.y*64;
  int zb = blockIdx.z;
  const float* xcol = (WSRC==1) ? (x1b_ + (size_t)zb*6144) : (const float*)nullptr;
  float* Cb = C + (size_t)zb*M*N2;
  float acc[4][4] = {};
  for(int k0=0;k0<Kd;k0+=32){
#pragma unroll
    for(int r=0;r<2;r++){
      int it = t + r*256;
      int m = it >> 3, kq = it & 7;
      int kg = k0 + kq*4;
      float4 v;
      if(ASRC==0){
        v = *(const float4*)&A[(size_t)(m0+m)*Kd + kg];
      } else {
        const float* src = (kg < 2048) ? (A + (size_t)(m0+m)*2048 + kg)
                                       : (A2 + (size_t)(m0+m)*2048 + (kg-2048));
        v = *(const float4*)src;
      }
      At[(kq*4+0)*68 + m] = v.x;
      At[(kq*4+1)*68 + m] = v.y;
      At[(kq*4+2)*68 + m] = v.z;
      At[(kq*4+3)*68 + m] = v.w;
    }
#pragma unroll
    for(int r=0;r<2;r++){
      int it = t + r*256;
      int nn = it >> 3, kq = it & 7;
      int kg = k0 + kq*4;
      if(WSRC==0){
        float4 v = *(const float4*)&Wm[(size_t)(n0+nn)*Kd + kg];
        Wt[(kq*4+0)*68 + nn] = v.x;
        Wt[(kq*4+1)*68 + nn] = v.y;
        Wt[(kq*4+2)*68 + nn] = v.z;
        Wt[(kq*4+3)*68 + nn] = v.w;
      } else {
        float xa = xcol[n0+nn], xb2 = xcol[2048 + n0+nn], xc = xcol[4096 + n0+nn];
#pragma unroll
        for(int d=0;d<4;d++){
          int k = kg + d;
          float v = c1w[k*3]*xa + c1w[k*3+1]*xb2 + c1w[k*3+2]*xc;
          Wt[(kq*4+d)*68 + nn] = gelu_f(v);
        }
      }
    }
    __syncthreads();
    int mm0 = (t & 15)*4, nn0 = (t >> 4)*4;
#pragma unroll 8
    for(int k=0;k<32;k++){
      float4 a = *(const float4*)&At[k*68 + mm0];
      float4 w = *(const float4*)&Wt[k*68 + nn0];
      float av[4] = {a.x,a.y,a.z,a.w};
      float wv[4] = {w.x,w.y,w.z,w.w};
#pragma unroll
      for(int i=0;i<4;i++)
#pragma unroll
        for(int j=0;j<4;j++) acc[i][j] += av[i]*wv[j];
    }
    __syncthreads();
  }
  int mm0 = (t & 15)*4, nn0 = (t >> 4)*4;
#pragma unroll
  for(int i=0;i<4;i++){
    int row = m0 + mm0 + i;
    size_t base = (size_t)row*N2 + n0 + nn0;
    float4 v = make_float4(acc[i][0], acc[i][1], acc[i][2], acc[i][3]);
    if(bias){
      v.x += bias[n0+nn0+0]; v.y += bias[n0+nn0+1];
      v.z += bias[n0+nn0+2]; v.w += bias[n0+nn0+3];
    }
    if(EPI==1){
      v.x = gelu_f(v.x); v.y = gelu_f(v.y); v.z = gelu_f(v.z); v.w = gelu_f(v.w);
    }
    if(EPI==2){
      float4 rv = *(const float4*)&resid[(size_t)zb*M*N2 + base];
      v.x += rv.x; v.y += rv.y; v.z += rv.z; v.w += rv.w;
    }
    *(float4*)&Cb[base] = v;
  }
}

// ---------------- k_attn2: per (b,h) full 128x128 attention ----------------
__global__ __launch_bounds__(256) void k_attn2(const float* __restrict__ qkv, float* __restrict__ obuf)
{
  __shared__ float smem[24960];
  float* qt = smem;              // [32][132]
  float* kt = smem + 4224;       // [32][132]
  float* smat = smem + 8448;     // [128][129]
  int b = blockIdx.x >> 3, h = blockIdx.x & 7;
  int t = threadIdx.x;
  const float* qb = qkv + (size_t)b*128*6144 + h*256;
  float acc[8][8] = {};
  int nn0 = (t & 15)*8, mm0 = (t >> 4)*8;
  for(int d0=0; d0<256; d0+=32){
#pragma unroll
    for(int r=0;r<4;r++){
      int it = t + r*256;
      int n = it >> 3, dq = it & 7;
      float4 qv = *(const float4*)&qb[(size_t)n*6144 + d0 + dq*4];
      float4 kv = *(const float4*)&qb[(size_t)n*6144 + 2048 + d0 + dq*4];
      qt[(dq*4+0)*132 + n] = qv.x; qt[(dq*4+1)*132 + n] = qv.y;
      qt[(dq*4+2)*132 + n] = qv.z; qt[(dq*4+3)*132 + n] = qv.w;
      kt[(dq*4+0)*132 + n] = kv.x; kt[(dq*4+1)*132 + n] = kv.y;
      kt[(dq*4+2)*132 + n] = kv.z; kt[(dq*4+3)*132 + n] = kv.w;
    }
    __syncthreads();
#pragma unroll 4
    for(int d=0; d<32; d++){
      float4 a0 = *(const float4*)&qt[d*132 + nn0];
      float4 a1 = *(const float4*)&qt[d*132 + nn0 + 4];
      float4 w0 = *(const float4*)&kt[d*132 + mm0];
      float4 w1 = *(const float4*)&kt[d*132 + mm0 + 4];
      float av[8] = {a0.x,a0.y,a0.z,a0.w,a1.x,a1.y,a1.z,a1.w};
      float wv[8] = {w0.x,w0.y,w0.z,w0.w,w1.x,w1.y,w1.z,w1.w};
#pragma unroll
      for(int i=0;i<8;i++)
#pragma unroll
        for(int j=0;j<8;j++) acc[i][j] += av[i]*wv[j];
    }
    __syncthreads();
  }
#pragma unroll
  for(int i=0;i<8;i++)
#pragma unroll
    for(int j=0;j<8;j++) smat[(size_t)(nn0+i)*129 + mm0+j] = acc[i][j] * 0.0625f;
  __syncthreads();
  {
    int row = t >> 1, half = t & 1;
    float* sr = &smat[(size_t)row*129 + half*64];
    float mx = -3.0e38f;
    for(int c=0;c<64;c++) mx = fmaxf(mx, sr[c]);
    mx = fmaxf(mx, __shfl_xor(mx, 1));
    float sum = 0.f;
    for(int c=0;c<64;c++){ float e = expf(sr[c]-mx); sr[c] = e; sum += e; }
    sum += __shfl_xor(sum, 1);
    float inv = 1.f/sum;
    for(int c=0;c<64;c++) sr[c] *= inv;
  }
  __syncthreads();
  float* vt = smem;              // reuse qt (4224 >= 32*132)
  int dd0 = (t >> 4)*8;
  for(int dh=0; dh<2; dh++){
    float acc2[8][8] = {};
    for(int mc=0; mc<4; mc++){
#pragma unroll
      for(int r=0;r<4;r++){
        int it = t + r*256;
        int m = it >> 5, dq = it & 31;
        float4 v = *(const float4*)&qb[(size_t)(mc*32+m)*6144 + 4096 + dh*128 + dq*4];
        *(float4*)&vt[m*132 + dq*4] = v;
      }
      __syncthreads();
#pragma unroll 4
      for(int ml=0; ml<32; ml++){
        float pv[8];
#pragma unroll
        for(int i=0;i<8;i++) pv[i] = smat[(size_t)(nn0+i)*129 + mc*32 + ml];
        float4 v0 = *(const float4*)&vt[ml*132 + dd0];
        float4 v1 = *(const float4*)&vt[ml*132 + dd0 + 4];
        float wv[8] = {v0.x,v0.y,v0.z,v0.w,v1.x,v1.y,v1.z,v1.w};
#pragma unroll
        for(int i=0;i<8;i++)
#pragma unroll
          for(int j=0;j<8;j++) acc2[i][j] += pv[i]*wv[j];
      }
      __syncthreads();
    }
#pragma unroll
    for(int i=0;i<8;i++){
      size_t base = (size_t)(b*128 + nn0+i)*2048 + h*256 + dh*128 + dd0;
      *(float4*)&obuf[base]   = make_float4(acc2[i][0],acc2[i][1],acc2[i][2],acc2[i][3]);
      *(float4*)&obuf[base+4] = make_float4(acc2[i][4],acc2[i][5],acc2[i][6],acc2[i][7]);
    }
  }
}

// ---------------- k_fps: farthest point sampling, 1024 of 2048, exact argmax semantics ----------------
__global__ __launch_bounds__(256) void k_fps(const float* __restrict__ x, int* __restrict__ fpsidx)
{
  __shared__ float xs[2048], ys[2048], zs[2048];
  __shared__ float rv[2][4];
  __shared__ int ri[2][4];
  int b = blockIdx.x, t = threadIdx.x;
  const float* xb = x + (size_t)b*6144;
  float px[8], py[8], pz[8], dm[8];
#pragma unroll
  for(int u=0;u<8;u++){
    int j = u*256 + t;
    float a = xb[j], c = xb[2048+j], d = xb[4096+j];
    xs[j]=a; ys[j]=c; zs[j]=d;
    px[u]=a; py[u]=c; pz[u]=d;
    dm[u] = 1e10f;
  }
  if(t==0) fpsidx[b*1024] = 0;
  __syncthreads();
  int last = 0;
  int w = t>>6, l = t&63;
  for(int it=1; it<1024; it++){
    float lx = xs[last], ly = ys[last], lz = zs[last];
    float best = -1.f; int bi = 0;
#pragma unroll
    for(int u=0;u<8;u++){
      float dx = px[u]-lx, dy = py[u]-ly, dz = pz[u]-lz;
      float d = __fadd_rn(__fadd_rn(__fmul_rn(dx,dx), __fmul_rn(dy,dy)), __fmul_rn(dz,dz));
      float nd = fminf(dm[u], d);
      dm[u] = nd;
      if(nd > best){ best = nd; bi = u*256 + t; }
    }
#pragma unroll
    for(int m=1;m<64;m<<=1){
      float ov = __shfl_xor(best, m); int oi = __shfl_xor(bi, m);
      if(ov > best || (ov == best && oi < bi)){ best = ov; bi = oi; }
    }
    int par = it & 1;
    if(l==0){ rv[par][w] = best; ri[par][w] = bi; }
    __syncthreads();
    float bv = rv[par][0]; int bidx = ri[par][0];
#pragma unroll
    for(int ww=1; ww<4; ww++){
      float v2 = rv[par][ww]; int i2 = ri[par][ww];
      if(v2 > bv || (v2 == bv && i2 < bidx)){ bv = v2; bidx = i2; }
    }
    last = bidx;
    if(t==0) fpsidx[b*1024 + it] = last;
  }
}

// ---------------- k_gather: final column gather into outputs ----------------
__global__ __launch_bounds__(256) void k_gather(const float* __restrict__ x,
    const float* __restrict__ y, const int* __restrict__ fpsidx, float* __restrict__ out)
{
  int i = blockIdx.x*256 + threadIdx.x;       // 524288 threads
  if(i < 12288){
    int b = i / 3072, rem = i - b*3072, c = rem >> 10, m = rem & 1023;
    int j = fpsidx[b*1024 + m];
    out[i] = x[(size_t)b*6144 + c*2048 + j];
  }
  {
    int b = i >> 17, rem = i & 131071, c = rem >> 10, m = rem & 1023;
    int j = fpsidx[b*1024 + m];
    out[12288 + i] = y[((size_t)(b*128 + c))*2048 + j];
  }
}

// ---------------- launcher ----------------
extern "C" void kernel_launch(void* const* d_in, const int* in_sizes, int n_in,
                              void* d_out, int out_size, void* d_ws, size_t ws_size,
                              hipStream_t stream) {
  (void)in_sizes; (void)n_in; (void)out_size; (void)ws_size;
  const float* x      = (const float*)d_in[0];
  const float* w_it   = (const float*)d_in[1];
  const float* b_it   = (const float*)d_in[2];
  const float* wl1    = (const float*)d_in[3];
  const float* gn1_g  = (const float*)d_in[4];
  const float* gn1_b  = (const float*)d_in[5];
  const float* wl2    = (const float*)d_in[6];
  const float* gn2_g  = (const float*)d_in[7];
  const float* gn2_b  = (const float*)d_in[8];
  const float* e1_n1g = (const float*)d_in[9];
  const float* e1_n1b = (const float*)d_in[10];
  const float* e1_qkv = (const float*)d_in[11];
  const float* e1_pw  = (const float*)d_in[12];
  const float* e1_pb  = (const float*)d_in[13];
  const float* e1_mw  = (const float*)d_in[14];
  const float* e1_mb  = (const float*)d_in[15];
  const float* e1_c1  = (const float*)d_in[16];
  const float* e1_c2  = (const float*)d_in[17];
  const float* e1_n2g = (const float*)d_in[18];
  const float* e1_n2b = (const float*)d_in[19];
  const float* e1_f1w = (const float*)d_in[20];
  const float* e1_f1b = (const float*)d_in[21];
  const float* e1_f2w = (const float*)d_in[22];
  const float* e1_f2b = (const float*)d_in[23];
  const float* e2_n1g = (const float*)d_in[24];
  const float* e2_n1b = (const float*)d_in[25];
  const float* e2_qkv = (const float*)d_in[26];
  const float* e2_pw  = (const float*)d_in[27];
  const float* e2_pb  = (const float*)d_in[28];
  const float* e2_n2g = (const float*)d_in[29];
  const float* e2_n2b = (const float*)d_in[30];
  const float* e2_f1w = (const float*)d_in[31];
  const float* e2_f1b = (const float*)d_in[32];
  const float* e2_f2w = (const float*)d_in[33];
  const float* e2_f2b = (const float*)d_in[34];

  float* p = (float*)d_ws;
  float* ft     = p; p += 262144;
  float* sq     = p; p += 8192;
  int*   knnidx = (int*)p; p += 131072;
  float* nx     = p; p += 24576;
  float* qkv1   = p; p += 73728;
  float* obuf1  = p; p += 24576;
  float* x1     = p; p += 24576;
  float* s1     = p; p += 1024;
  float* t1     = p; p += 1024;
  float* s2     = p; p += 512;
  float* t2     = p; p += 512;
  float* part1  = p; p += 32768;
  float* part2  = p; p += 32768;
  float* hmax   = p; p += 1048576;
  float* hmin   = p; p += 1048576;
  float* knnf   = p; p += 1048576;
  float* h1     = p; p += 1048576;
  float* ybuf   = p; p += 1048576;
  float* lnbuf  = p; p += 1048576;
  float* hbuf   = p; p += 2097152;
  float* qkvbuf = p; p += 3145728;
  float* obuf2  = p; p += 1048576;
  int*   fpsidx = (int*)p; p += 4096;
  float* out    = (float*)d_out;

  k_ft_sq<<<32,256,0,stream>>>(x, w_it, b_it, ft, sq);
  k_knn<<<2048,256,0,stream>>>(x, sq, knnidx);
  k_ln<<<12,256,0,stream>>>(x, e1_n1g, e1_n1b, nx);
  k_qkv1<<<1536,256,0,stream>>>(nx, e1_qkv, qkv1);
  k_attn1<<<32,256,0,stream>>>(qkv1, obuf1);
  k_proj1<<<512,256,0,stream>>>(nx, obuf1, e1_pw, e1_pb, x1);
  k_convknn<0><<<4096,256,0,stream>>>(ft, knnidx, wl1, wl2, nullptr, nullptr,
                                      part1, nullptr, nullptr, nullptr);
  k_gn1fin<<<1,256,0,stream>>>(part1, gn1_g, gn1_b, s1, t1);
  k_convknn<1><<<4096,256,0,stream>>>(ft, knnidx, wl1, wl2, s1, t1,
                                      part1, part2, hmax, hmin);
  k_gn2fin<<<1,256,0,stream>>>(part2, gn2_g, gn2_b, s2, t2);
  k_knnf<<<1024,256,0,stream>>>(hmax, hmin, s2, t2, knnf);
  // h1 = e1_c2 @ gelu(e1_c1 @ x1)   (per batch)
  k_gemm<0,1,0><<<dim3(32,2,4),256,0,stream>>>(e1_c2, nullptr, nullptr, x1, e1_c1,
                                               nullptr, nullptr, h1, 128, 2048, 512);
  // y = h1 + concat(h1,knnf) @ e1_mw^T + e1_mb
  k_gemm<1,0,2><<<dim3(32,8,1),256,0,stream>>>(h1, knnf, e1_mw, nullptr, nullptr,
                                               e1_mb, h1, ybuf, 512, 2048, 4096);
  // MLP 1
  k_ln<<<512,256,0,stream>>>(ybuf, e1_n2g, e1_n2b, lnbuf);
  k_gemm<0,0,1><<<dim3(64,8,1),256,0,stream>>>(lnbuf, nullptr, e1_f1w, nullptr, nullptr,
                                               e1_f1b, nullptr, hbuf, 512, 4096, 2048);
  k_gemm<0,0,2><<<dim3(32,8,1),256,0,stream>>>(hbuf, nullptr, e1_f2w, nullptr, nullptr,
                                               e1_f2b, ybuf, ybuf, 512, 2048, 4096);
  // attention 2
  k_ln<<<512,256,0,stream>>>(ybuf, e2_n1g, e2_n1b, lnbuf);
  k_gemm<0,0,0><<<dim3(96,8,1),256,0,stream>>>(lnbuf, nullptr, e2_qkv, nullptr, nullptr,
                                               nullptr, nullptr, qkvbuf, 512, 6144, 2048);
  k_attn2<<<32,256,0,stream>>>(qkvbuf, obuf2);
  k_gemm<0,0,2><<<dim3(32,8,1),256,0,stream>>>(obuf2, nullptr, e2_pw, nullptr, nullptr,
                                               e2_pb, ybuf, ybuf, 512, 2048, 2048);
  // MLP 2
  k_ln<<<512,256,0,stream>>>(ybuf, e2_n2g, e2_n2b, lnbuf);
  k_gemm<0,0,1><<<dim3(64,8,1),256,0,stream>>>(lnbuf, nullptr, e2_f1w, nullptr, nullptr,
                                               e2_f1b, nullptr, hbuf, 512, 4096, 2048);
  k_gemm<0,0,2><<<dim3(32,8,1),256,0,stream>>>(hbuf, nullptr, e2_f2w, nullptr, nullptr,
                                               e2_f2b, ybuf, ybuf, 512, 2048, 4096);
  // FPS + gather
  k_fps<<<4,256,0,stream>>>(x, fpsidx);
  k_gather<<<2048,256,0,stream>>>(x, ybuf, fpsidx, out);
}

// Round 6
// 2590.770 us; speedup vs baseline: 1.2106x; 1.2106x over previous
//
#include <hip/hip_runtime.h>
#include <math.h>

#define DEV static __device__ __forceinline__

// ---------------- helpers ----------------
DEV float wsum(float v){
#pragma unroll
  for(int m=32;m>=1;m>>=1) v += __shfl_xor(v, m);
  return v;
}
DEV float gelu_f(float v){
  return 0.5f*v*(1.0f + erff(v*0.70710678118654752440f));
}

// ---------------- k_ft_sq: f = w_it@x + b_it (stored transposed ft[b][n][c]), sq = sum(x^2) ----------------
__global__ __launch_bounds__(256) void k_ft_sq(
    const float* __restrict__ x, const float* __restrict__ w_it,
    const float* __restrict__ b_it, float* __restrict__ ft, float* __restrict__ sq)
{
  int g = blockIdx.x*256 + threadIdx.x;      // 8192 = B*N
  int b = g >> 11, n = g & 2047;
  const float* xb = x + (size_t)b*6144;
  float x0 = xb[n], x1v = xb[2048+n], x2 = xb[4096+n];
  sq[g] = x0*x0 + x1v*x1v + x2*x2;
  float* o = ft + (size_t)g*32;
#pragma unroll
  for(int c=0;c<32;c++)
    o[c] = w_it[c*3]*x0 + w_it[c*3+1]*x1v + w_it[c*3+2]*x2 + b_it[c];
}

// ---------------- k_knn: top-16 nearest (incl self), top_k tie semantics ----------------
__global__ __launch_bounds__(256) void k_knn(
    const float* __restrict__ x, const float* __restrict__ sq, int* __restrict__ knnidx)
{
  __shared__ float dbuf[4][2048];
  int w = threadIdx.x >> 6, l = threadIdx.x & 63;
  int row = blockIdx.x*4 + w;                // b*2048+n
  int b = row >> 11, n = row & 2047;
  const float* xb = x + (size_t)b*6144;
  const float* sqb = sq + (size_t)b*2048;
  float px = xb[n], py = xb[2048+n], pz = xb[4096+n], sqi = sqb[n];
  for(int j = l; j < 2048; j += 64){
    float dot = xb[j]*px + xb[2048+j]*py + xb[4096+j]*pz;
    dbuf[w][j] = sqi - 2.0f*dot + sqb[j];
  }
  __syncthreads();
  const float INFV = 3.0e38f;
  int* orow = knnidx + (size_t)row*16;
  int base = l*32;
  for(int r=0;r<16;r++){
    float best = INFV; int bi = 0;
#pragma unroll
    for(int u=0;u<8;u++){
      float4 v = *(const float4*)&dbuf[w][base + u*4];
      int j0 = base + u*4;
      if(v.x < best){best=v.x; bi=j0;}
      if(v.y < best){best=v.y; bi=j0+1;}
      if(v.z < best){best=v.z; bi=j0+2;}
      if(v.w < best){best=v.w; bi=j0+3;}
    }
#pragma unroll
    for(int m=1;m<64;m<<=1){
      float ov = __shfl_xor(best, m); int oi = __shfl_xor(bi, m);
      if(ov < best || (ov == best && oi < bi)){ best = ov; bi = oi; }
    }
    if(l==0){ orow[r] = bi; dbuf[w][bi] = INFV; }
    __syncthreads();
  }
}

// ---------------- k_ln: LayerNorm over last dim 2048 ----------------
__global__ __launch_bounds__(256) void k_ln(const float* __restrict__ in,
    const float* __restrict__ g, const float* __restrict__ bb, float* __restrict__ out)
{
  int row = blockIdx.x, t = threadIdx.x;
  const float4* in4 = (const float4*)(in + (size_t)row*2048);
  float4 a = in4[t], c = in4[t+256];
  float sm = a.x+a.y+a.z+a.w + c.x+c.y+c.z+c.w;
  float ssq = a.x*a.x+a.y*a.y+a.z*a.z+a.w*a.w + c.x*c.x+c.y*c.y+c.z*c.z+c.w*c.w;
  sm = wsum(sm); ssq = wsum(ssq);
  __shared__ float sh[8];
  int w = t>>6, l = t&63;
  if(l==0){ sh[w] = sm; sh[4+w] = ssq; }
  __syncthreads();
  sm = sh[0]+sh[1]+sh[2]+sh[3];
  ssq = sh[4]+sh[5]+sh[6]+sh[7];
  float mean = sm * (1.f/2048.f);
  float rs = rsqrtf(ssq*(1.f/2048.f) - mean*mean + 1e-5f);
  const float4* g4 = (const float4*)g; const float4* b4 = (const float4*)bb;
  float4* o4 = (float4*)(out + (size_t)row*2048);
  float4 g0 = g4[t], b0 = b4[t], g1 = g4[t+256], b1 = b4[t+256];
  float4 r0, r1;
  r0.x=(a.x-mean)*rs*g0.x+b0.x; r0.y=(a.y-mean)*rs*g0.y+b0.y;
  r0.z=(a.z-mean)*rs*g0.z+b0.z; r0.w=(a.w-mean)*rs*g0.w+b0.w;
  r1.x=(c.x-mean)*rs*g1.x+b1.x; r1.y=(c.y-mean)*rs*g1.y+b1.y;
  r1.z=(c.z-mean)*rs*g1.z+b1.z; r1.w=(c.w-mean)*rs*g1.w+b1.w;
  o4[t] = r0; o4[t+256] = r1;
}

// ---------------- k_qkv1: qkv1 = nx @ W^T (12 rows), wave per W-row ----------------
__global__ __launch_bounds__(256) void k_qkv1(
    const float* __restrict__ nx, const float* __restrict__ W, float* __restrict__ outq)
{
  int w = threadIdx.x>>6, l = threadIdx.x&63;
  int c = blockIdx.x*4 + w;                  // 6144
  const float4* wrow = (const float4*)(W + (size_t)c*2048);
  float acc[12];
#pragma unroll
  for(int r=0;r<12;r++) acc[r]=0.f;
  for(int it=0; it<8; it++){
    int k4 = it*64 + l;
    float4 wv = wrow[k4];
#pragma unroll
    for(int r=0;r<12;r++){
      float4 a = ((const float4*)(nx + (size_t)r*2048))[k4];
      acc[r] += a.x*wv.x + a.y*wv.y + a.z*wv.z + a.w*wv.w;
    }
  }
#pragma unroll
  for(int r=0;r<12;r++) acc[r] = wsum(acc[r]);
  if(l==0){
#pragma unroll
    for(int r=0;r<12;r++) outq[(size_t)r*6144 + c] = acc[r];
  }
}

// ---------------- k_attn1: tiny attention over seq len 3 ----------------
__global__ __launch_bounds__(256) void k_attn1(const float* __restrict__ qkv1, float* __restrict__ obuf)
{
  int b = blockIdx.x >> 3, h = blockIdx.x & 7;
  __shared__ float s[3][3], p[3][3];
  int t = threadIdx.x; int w = t>>6, l = t&63;
  for(int dot = w; dot < 9; dot += 4){
    int n = dot/3, m = dot - n*3;
    const float* q = qkv1 + (size_t)(b*3+n)*6144 + h*256;
    const float* k = qkv1 + (size_t)(b*3+m)*6144 + 2048 + h*256;
    float4 qv = ((const float4*)q)[l];
    float4 kv = ((const float4*)k)[l];
    float a = qv.x*kv.x + qv.y*kv.y + qv.z*kv.z + qv.w*kv.w;
    a = wsum(a);
    if(l==0) s[n][m] = a * 0.0625f;
  }
  __syncthreads();
  if(t < 3){
    float m0 = fmaxf(s[t][0], fmaxf(s[t][1], s[t][2]));
    float e0 = expf(s[t][0]-m0), e1 = expf(s[t][1]-m0), e2 = expf(s[t][2]-m0);
    float inv = 1.f/(e0+e1+e2);
    p[t][0]=e0*inv; p[t][1]=e1*inv; p[t][2]=e2*inv;
  }
  __syncthreads();
  for(int i=t; i<768; i+=256){
    int n = i>>8, d = i&255;
    float o = 0.f;
#pragma unroll
    for(int m=0;m<3;m++) o += p[n][m] * qkv1[(size_t)(b*3+m)*6144 + 4096 + h*256 + d];
    obuf[(size_t)(b*3+n)*2048 + h*256 + d] = o;
  }
}

// ---------------- k_proj1: x1 = (nx - o) @ pw^T + pb, wave per W-row ----------------
__global__ __launch_bounds__(256) void k_proj1(
    const float* __restrict__ nx, const float* __restrict__ ob,
    const float* __restrict__ W, const float* __restrict__ bias, float* __restrict__ x1)
{
  int w = threadIdx.x>>6, l = threadIdx.x&63;
  int c = blockIdx.x*4 + w;                  // 2048
  const float4* wrow = (const float4*)(W + (size_t)c*2048);
  float acc[12];
#pragma unroll
  for(int r=0;r<12;r++) acc[r]=0.f;
  for(int it=0; it<8; it++){
    int k4 = it*64 + l;
    float4 wv = wrow[k4];
#pragma unroll
    for(int r=0;r<12;r++){
      float4 a = ((const float4*)(nx + (size_t)r*2048))[k4];
      float4 o = ((const float4*)(ob + (size_t)r*2048))[k4];
      acc[r] += (a.x-o.x)*wv.x + (a.y-o.y)*wv.y + (a.z-o.z)*wv.z + (a.w-o.w)*wv.w;
    }
  }
#pragma unroll
  for(int r=0;r<12;r++) acc[r] = wsum(acc[r]);
  if(l==0){
#pragma unroll
    for(int r=0;r<12;r++) x1[(size_t)r*2048 + c] = acc[r] + bias[c];
  }
}

// ---------------- fused graph-conv: conv1(+stats) / conv1->gn1->leaky->conv2->stats2+maxmin ----------------
template<int FULL>
__global__ __launch_bounds__(256) void k_convknn(
    const float* __restrict__ ft, const int* __restrict__ knnidx,
    const float* __restrict__ wl1, const float* __restrict__ wl2,
    const float* __restrict__ s1, const float* __restrict__ t1,
    float* __restrict__ part1, float* __restrict__ part2,
    float* __restrict__ hmax, float* __restrict__ hmin)
{
  __shared__ float smem[19712];
  float* gfT = smem;              // [64][36]
  float* w1t = smem + 2304;       // [64][260]
  float* a1T = smem;              // [256][36] (phase2 alias)
  float* w2t = smem + 9216;       // [64][132]
  float* mmb = smem + 17664;      // 2048

  int t = threadIdx.x;
  int posBase = blockIdx.x * 32;
  int b = posBase >> 15;

#pragma unroll
  for(int r=0;r<2;r++){
    int it = t + r*256;
    int pos = it & 31, cq = it >> 5;
    int s = posBase + pos;
    int n = (s >> 4) & 2047;
    float4 v;
    if(cq < 8){
      int j = knnidx[s];
      float4 aj = *(const float4*)&ft[((size_t)(b*2048 + j))*32 + cq*4];
      float4 an = *(const float4*)&ft[((size_t)(b*2048 + n))*32 + cq*4];
      v = make_float4(aj.x-an.x, aj.y-an.y, aj.z-an.z, aj.w-an.w);
    } else {
      v = *(const float4*)&ft[((size_t)(b*2048 + n))*32 + (cq-8)*4];
    }
    int c0 = cq*4;
    gfT[(c0+0)*36 + pos] = v.x;
    gfT[(c0+1)*36 + pos] = v.y;
    gfT[(c0+2)*36 + pos] = v.z;
    gfT[(c0+3)*36 + pos] = v.w;
  }
#pragma unroll
  for(int r=0;r<16;r++){
    int it = t + r*256;
    int ch = it & 255, kq = it >> 8;
    float4 v = *(const float4*)&wl1[(size_t)ch*64 + kq*4];
    w1t[(kq*4+0)*260 + ch] = v.x;
    w1t[(kq*4+1)*260 + ch] = v.y;
    w1t[(kq*4+2)*260 + ch] = v.z;
    w1t[(kq*4+3)*260 + ch] = v.w;
  }
  __syncthreads();

  int pos0 = (t & 7)*4, ch0 = (t >> 3)*8;
  float acc[4][8] = {};
#pragma unroll 4
  for(int k=0;k<64;k++){
    float4 a = *(const float4*)&gfT[k*36 + pos0];
    float4 w0 = *(const float4*)&w1t[(size_t)k*260 + ch0];
    float4 w1v = *(const float4*)&w1t[(size_t)k*260 + ch0 + 4];
    float av[4] = {a.x,a.y,a.z,a.w};
    float wv[8] = {w0.x,w0.y,w0.z,w0.w,w1v.x,w1v.y,w1v.z,w1v.w};
#pragma unroll
    for(int p=0;p<4;p++)
#pragma unroll
      for(int c=0;c<8;c++) acc[p][c] += av[p]*wv[c];
  }
  if(!FULL){
    float sm=0.f, ssq=0.f;
#pragma unroll
    for(int p=0;p<4;p++)
#pragma unroll
      for(int c=0;c<8;c++){ float v = acc[p][c]; sm += v; ssq += v*v; }
    sm = wsum(sm); ssq = wsum(ssq);
    int w = t >> 6, l = t & 63;
    if(l==0){ part1[(size_t)blockIdx.x*8 + w*2] = sm; part1[(size_t)blockIdx.x*8 + w*2 + 1] = ssq; }
    return;
  }
  float sv[8], tv[8];
#pragma unroll
  for(int c=0;c<8;c++){ sv[c] = s1[b*256 + ch0 + c]; tv[c] = t1[b*256 + ch0 + c]; }
  __syncthreads();          // all GEMM1 LDS reads done before a1T overwrite
#pragma unroll
  for(int c=0;c<8;c++){
#pragma unroll
    for(int p=0;p<4;p++){
      float a = sv[c]*acc[p][c] + tv[c];
      a = a >= 0.f ? a : 0.2f*a;
      a1T[(size_t)(ch0+c)*36 + pos0 + p] = a;
    }
  }
  float acc2[4][4] = {};
  int oc0 = (t >> 3)*4;
  for(int cc=0; cc<4; cc++){
#pragma unroll
    for(int r=0;r<8;r++){
      int it = t + r*256;
      int ch = it & 127, kq = it >> 7;
      float4 v = *(const float4*)&wl2[(size_t)ch*256 + cc*64 + kq*4];
      w2t[(kq*4+0)*132 + ch] = v.x;
      w2t[(kq*4+1)*132 + ch] = v.y;
      w2t[(kq*4+2)*132 + ch] = v.z;
      w2t[(kq*4+3)*132 + ch] = v.w;
    }
    __syncthreads();
#pragma unroll 8
    for(int kk=0;kk<64;kk++){
      float4 a = *(const float4*)&a1T[(size_t)(cc*64+kk)*36 + pos0];
      float4 w = *(const float4*)&w2t[kk*132 + oc0];
      float av[4] = {a.x,a.y,a.z,a.w};
      float wv[4] = {w.x,w.y,w.z,w.w};
#pragma unroll
      for(int p=0;p<4;p++)
#pragma unroll
        for(int c=0;c<4;c++) acc2[p][c] += av[p]*wv[c];
    }
    __syncthreads();
  }
  {
    float sm=0.f, ssq=0.f;
#pragma unroll
    for(int p=0;p<4;p++)
#pragma unroll
      for(int c=0;c<4;c++){ float v = acc2[p][c]; sm += v; ssq += v*v; }
    sm = wsum(sm); ssq = wsum(ssq);
    int w = t >> 6, l = t & 63;
    if(l==0){ part2[(size_t)blockIdx.x*8 + w*2] = sm; part2[(size_t)blockIdx.x*8 + w*2 + 1] = ssq; }
  }
  float* maxb = mmb; float* minb = mmb + 1024;
  int nloc = pos0 >> 4, kg = (pos0 & 15) >> 2;
#pragma unroll
  for(int c=0;c<4;c++){
    float mx = fmaxf(fmaxf(acc2[0][c], acc2[1][c]), fmaxf(acc2[2][c], acc2[3][c]));
    float mn = fminf(fminf(acc2[0][c], acc2[1][c]), fminf(acc2[2][c], acc2[3][c]));
    maxb[(nloc*4 + kg)*128 + oc0 + c] = mx;
    minb[(nloc*4 + kg)*128 + oc0 + c] = mn;
  }
  __syncthreads();
  {
    int nl = t >> 7, c = t & 127;
    float mx = maxb[(nl*4+0)*128 + c];
    float mn = minb[(nl*4+0)*128 + c];
#pragma unroll
    for(int k2=1;k2<4;k2++){
      mx = fmaxf(mx, maxb[(nl*4+k2)*128 + c]);
      mn = fminf(mn, minb[(nl*4+k2)*128 + c]);
    }
    int n = ((posBase >> 4) & 2047) + nl;
    hmax[((size_t)(b*128 + c))*2048 + n] = mx;
    hmin[((size_t)(b*128 + c))*2048 + n] = mn;
  }
}

// ---------------- GN finalizers ----------------
__global__ __launch_bounds__(256) void k_gn1fin(const float* __restrict__ part,
    const float* __restrict__ g, const float* __restrict__ bb,
    float* __restrict__ s1, float* __restrict__ t1)
{
  __shared__ float sums[4][4][2];
  int t = threadIdx.x;
  if(t < 32){
    int b = t >> 3, gr = (t >> 1) & 3, wh = t & 1;
    float a = 0.f;
    for(int blk = b*1024; blk < (b+1)*1024; blk++) a += part[(size_t)blk*8 + gr*2 + wh];
    sums[b][gr][wh] = a;
  }
  __syncthreads();
  const float inv = 1.f/(64.f*32768.f);
  for(int i=t;i<1024;i+=256){
    int b = i >> 8, c = i & 255, gr = c >> 6;
    float mean = sums[b][gr][0]*inv;
    float var = sums[b][gr][1]*inv - mean*mean;
    float svv = g[c]*rsqrtf(var + 1e-5f);
    s1[b*256+c] = svv;
    t1[b*256+c] = bb[c] - mean*svv;
  }
}
__global__ __launch_bounds__(256) void k_gn2fin(const float* __restrict__ part,
    const float* __restrict__ g, const float* __restrict__ bb,
    float* __restrict__ s2, float* __restrict__ t2)
{
  __shared__ float sums[4][4][2];
  int t = threadIdx.x;
  if(t < 32){
    int b = t >> 3, gr = (t >> 1) & 3, wh = t & 1;
    float a = 0.f;
    for(int blk = b*1024; blk < (b+1)*1024; blk++) a += part[(size_t)blk*8 + gr*2 + wh];
    sums[b][gr][wh] = a;
  }
  __syncthreads();
  const float inv = 1.f/(32.f*32768.f);
  for(int i=t;i<512;i+=256){
    int b = i >> 7, c = i & 127, gr = c >> 5;
    float mean = sums[b][gr][0]*inv;
    float var = sums[b][gr][1]*inv - mean*mean;
    float svv = g[c]*rsqrtf(var + 1e-5f);
    s2[b*128+c] = svv;
    t2[b*128+c] = bb[c] - mean*svv;
  }
}

// ---------------- k_knnf: knn_f = leaky(gn2 applied to max/min) ----------------
__global__ __launch_bounds__(256) void k_knnf(const float* __restrict__ hmax,
    const float* __restrict__ hmin, const float* __restrict__ s2,
    const float* __restrict__ t2, float* __restrict__ knnf)
{
  int i = blockIdx.x*256 + threadIdx.x;       // 262144 float4 groups
  int bc = i >> 9;
  int b = bc >> 7, c = bc & 127;
  float s = s2[b*128+c], tt = t2[b*128+c];
  float4 mx = ((const float4*)hmax)[i], mn = ((const float4*)hmin)[i];
  float4 v = (s >= 0.f) ? mx : mn;
  float4 r;
  r.x = s*v.x + tt; r.y = s*v.y + tt; r.z = s*v.z + tt; r.w = s*v.w + tt;
  r.x = r.x >= 0.f ? r.x : 0.2f*r.x;
  r.y = r.y >= 0.f ? r.y : 0.2f*r.y;
  r.z = r.z >= 0.f ? r.z : 0.2f*r.z;
  r.w = r.w >= 0.f ? r.w : 0.2f*r.w;
  ((float4*)knnf)[i] = r;
}

// ---------------- generic tiled SGEMM-BT: C = epi(A @ W^T (+bias) (+resid)) ----------------
// ASRC: 0 direct (stride Kd) | 1 concat of A/A2 (each stride 2048)
// WSRC: 0 direct (W: N2 x Kd, K-contig) | 1 on-the-fly gelu(c1 @ x1) per batch z
// EPI:  0 none | 1 gelu | 2 +resid
template<int ASRC, int WSRC, int EPI>
__global__ __launch_bounds__(256) void k_gemm(
    const float* __restrict__ A, const float* __restrict__ A2,
    const float* __restrict__ Wm, const float* __restrict__ x1b_, const float* __restrict__ c1w,
    const float* __restrict__ bias, const float* __restrict__ resid,
    float* __restrict__ C, int M, int N2, int Kd)
{
  __shared__ float At[32*68], Wt[32*68];
  int t = threadIdx.x;
  int n0 = blockIdx.x*64, m0 = blockIdx.y*64;
  int zb = blockIdx.z;
  const float* xcol = (WSRC==1) ? (x1b_ + (size_t)zb*6144) : (const float*)nullptr;
  float* Cb = C + (size_t)zb*M*N2;
  float acc[4][4] = {};
  for(int k0=0;k0<Kd;k0+=32){
#pragma unroll
    for(int r=0;r<2;r++){
      int it = t + r*256;
      int m = it >> 3, kq = it & 7;
      int kg = k0 + kq*4;
      float4 v;
      if(ASRC==0){
        v = *(const float4*)&A[(size_t)(m0+m)*Kd + kg];
      } else {
        const float* src = (kg < 2048) ? (A + (size_t)(m0+m)*2048 + kg)
                                       : (A2 + (size_t)(m0+m)*2048 + (kg-2048));
        v = *(const float4*)src;
      }
      At[(kq*4+0)*68 + m] = v.x;
      At[(kq*4+1)*68 + m] = v.y;
      At[(kq*4+2)*68 + m] = v.z;
      At[(kq*4+3)*68 + m] = v.w;
    }
#pragma unroll
    for(int r=0;r<2;r++){
      int it = t + r*256;
      int nn = it >> 3, kq = it & 7;
      int kg = k0 + kq*4;
      if(WSRC==0){
        float4 v = *(const float4*)&Wm[(size_t)(n0+nn)*Kd + kg];
        Wt[(kq*4+0)*68 + nn] = v.x;
        Wt[(kq*4+1)*68 + nn] = v.y;
        Wt[(kq*4+2)*68 + nn] = v.z;
        Wt[(kq*4+3)*68 + nn] = v.w;
      } else {
        float xa = xcol[n0+nn], xb2 = xcol[2048 + n0+nn], xc = xcol[4096 + n0+nn];
#pragma unroll
        for(int d=0;d<4;d++){
          int k = kg + d;
          float v = c1w[k*3]*xa + c1w[k*3+1]*xb2 + c1w[k*3+2]*xc;
          Wt[(kq*4+d)*68 + nn] = gelu_f(v);
        }
      }
    }
    __syncthreads();
    int mm0 = (t & 15)*4, nn0 = (t >> 4)*4;
#pragma unroll 8
    for(int k=0;k<32;k++){
      float4 a = *(const float4*)&At[k*68 + mm0];
      float4 w = *(const float4*)&Wt[k*68 + nn0];
      float av[4] = {a.x,a.y,a.z,a.w};
      float wv[4] = {w.x,w.y,w.z,w.w};
#pragma unroll
      for(int i=0;i<4;i++)
#pragma unroll
        for(int j=0;j<4;j++) acc[i][j] += av[i]*wv[j];
    }
    __syncthreads();
  }
  int mm0 = (t & 15)*4, nn0 = (t >> 4)*4;
#pragma unroll
  for(int i=0;i<4;i++){
    int row = m0 + mm0 + i;
    size_t base = (size_t)row*N2 + n0 + nn0;
    float4 v = make_float4(acc[i][0], acc[i][1], acc[i][2], acc[i][3]);
    if(bias){
      v.x += bias[n0+nn0+0]; v.y += bias[n0+nn0+1];
      v.z += bias[n0+nn0+2]; v.w += bias[n0+nn0+3];
    }
    if(EPI==1){
      v.x = gelu_f(v.x); v.y = gelu_f(v.y); v.z = gelu_f(v.z); v.w = gelu_f(v.w);
    }
    if(EPI==2){
      float4 rv = *(const float4*)&resid[(size_t)zb*M*N2 + base];
      v.x += rv.x; v.y += rv.y; v.z += rv.z; v.w += rv.w;
    }
    *(float4*)&Cb[base] = v;
  }
}

// ---------------- k_attn2: per (b,h) full 128x128 attention ----------------
__global__ __launch_bounds__(256) void k_attn2(const float* __restrict__ qkv, float* __restrict__ obuf)
{
  __shared__ float smem[24960];
  float* qt = smem;              // [32][132]
  float* kt = smem + 4224;       // [32][132]
  float* smat = smem + 8448;     // [128][129]
  int b = blockIdx.x >> 3, h = blockIdx.x & 7;
  int t = threadIdx.x;
  const float* qb = qkv + (size_t)b*128*6144 + h*256;
  float acc[8][8] = {};
  int nn0 = (t & 15)*8, mm0 = (t >> 4)*8;
  for(int d0=0; d0<256; d0+=32){
#pragma unroll
    for(int r=0;r<4;r++){
      int it = t + r*256;
      int n = it >> 3, dq = it & 7;
      float4 qv = *(const float4*)&qb[(size_t)n*6144 + d0 + dq*4];
      float4 kv = *(const float4*)&qb[(size_t)n*6144 + 2048 + d0 + dq*4];
      qt[(dq*4+0)*132 + n] = qv.x; qt[(dq*4+1)*132 + n] = qv.y;
      qt[(dq*4+2)*132 + n] = qv.z; qt[(dq*4+3)*132 + n] = qv.w;
      kt[(dq*4+0)*132 + n] = kv.x; kt[(dq*4+1)*132 + n] = kv.y;
      kt[(dq*4+2)*132 + n] = kv.z; kt[(dq*4+3)*132 + n] = kv.w;
    }
    __syncthreads();
#pragma unroll 4
    for(int d=0; d<32; d++){
      float4 a0 = *(const float4*)&qt[d*132 + nn0];
      float4 a1 = *(const float4*)&qt[d*132 + nn0 + 4];
      float4 w0 = *(const float4*)&kt[d*132 + mm0];
      float4 w1 = *(const float4*)&kt[d*132 + mm0 + 4];
      float av[8] = {a0.x,a0.y,a0.z,a0.w,a1.x,a1.y,a1.z,a1.w};
      float wv[8] = {w0.x,w0.y,w0.z,w0.w,w1.x,w1.y,w1.z,w1.w};
#pragma unroll
      for(int i=0;i<8;i++)
#pragma unroll
        for(int j=0;j<8;j++) acc[i][j] += av[i]*wv[j];
    }
    __syncthreads();
  }
#pragma unroll
  for(int i=0;i<8;i++)
#pragma unroll
    for(int j=0;j<8;j++) smat[(size_t)(nn0+i)*129 + mm0+j] = acc[i][j] * 0.0625f;
  __syncthreads();
  {
    int row = t >> 1, half = t & 1;
    float* sr = &smat[(size_t)row*129 + half*64];
    float mx = -3.0e38f;
    for(int c=0;c<64;c++) mx = fmaxf(mx, sr[c]);
    mx = fmaxf(mx, __shfl_xor(mx, 1));
    float sum = 0.f;
    for(int c=0;c<64;c++){ float e = expf(sr[c]-mx); sr[c] = e; sum += e; }
    sum += __shfl_xor(sum, 1);
    float inv = 1.f/sum;
    for(int c=0;c<64;c++) sr[c] *= inv;
  }
  __syncthreads();
  float* vt = smem;              // reuse qt (4224 >= 32*132)
  int dd0 = (t >> 4)*8;
  for(int dh=0; dh<2; dh++){
    float acc2[8][8] = {};
    for(int mc=0; mc<4; mc++){
#pragma unroll
      for(int r=0;r<4;r++){
        int it = t + r*256;
        int m = it >> 5, dq = it & 31;
        float4 v = *(const float4*)&qb[(size_t)(mc*32+m)*6144 + 4096 + dh*128 + dq*4];
        *(float4*)&vt[m*132 + dq*4] = v;
      }
      __syncthreads();
#pragma unroll 4
      for(int ml=0; ml<32; ml++){
        float pv[8];
#pragma unroll
        for(int i=0;i<8;i++) pv[i] = smat[(size_t)(nn0+i)*129 + mc*32 + ml];
        float4 v0 = *(const float4*)&vt[ml*132 + dd0];
        float4 v1 = *(const float4*)&vt[ml*132 + dd0 + 4];
        float wv[8] = {v0.x,v0.y,v0.z,v0.w,v1.x,v1.y,v1.z,v1.w};
#pragma unroll
        for(int i=0;i<8;i++)
#pragma unroll
          for(int j=0;j<8;j++) acc2[i][j] += pv[i]*wv[j];
      }
      __syncthreads();
    }
#pragma unroll
    for(int i=0;i<8;i++){
      size_t base = (size_t)(b*128 + nn0+i)*2048 + h*256 + dh*128 + dd0;
      *(float4*)&obuf[base]   = make_float4(acc2[i][0],acc2[i][1],acc2[i][2],acc2[i][3]);
      *(float4*)&obuf[base+4] = make_float4(acc2[i][4],acc2[i][5],acc2[i][6],acc2[i][7]);
    }
  }
}

// ---------------- k_fps: farthest point sampling, DPP wave-max + ballot argmax ----------------
// Per iteration the critical path is: 1 broadcast ds_read_b128 (coords of `last`)
// -> 8 register distance updates -> DPP f32 max (row_ror 1/2/4/8 + bcast15/31,
// all VALU-class, ~50cy vs ~1440cy for the old 12x ds-routed shuffle butterfly)
// -> readlane + ballot/ffs for exact first-occurrence argmax -> LDS cross-wave
// combine (parity double-buffered, 1 barrier). Point layout j = t*8+u is
// lane-major so (wave, lane, u) lexicographic order == j order; strict >
// comparisons everywhere reproduce jnp.argmax first-max semantics exactly.
// Distance arithmetic is bit-identical to the validated version.
__global__ __launch_bounds__(256) void k_fps(const float* __restrict__ x, int* __restrict__ fpsidx)
{
  __shared__ float4 pts[2048];
  __shared__ float bval[2][4];
  __shared__ int bidx[2][4];
  int b = blockIdx.x, t = threadIdx.x;
  int w = t>>6, l = t&63;
  const float* xb = x + (size_t)b*6144;
  float px[8], py[8], pz[8], dm[8];
#pragma unroll
  for(int u=0;u<8;u++){
    int j = t*8 + u;
    float a = xb[j], c = xb[2048+j], d = xb[4096+j];
    pts[j] = make_float4(a, c, d, 0.f);
    px[u]=a; py[u]=c; pz[u]=d;
    dm[u] = 1e10f;
  }
  if(t==0) fpsidx[b*1024] = 0;
  __syncthreads();
  int last = 0;
  for(int it=1; it<1024; it++){
    float4 P = pts[last];                      // uniform addr -> broadcast read
    float lmax = -1.f;
#pragma unroll
    for(int u=0;u<8;u++){
      float dx = px[u]-P.x, dy = py[u]-P.y, dz = pz[u]-P.z;
      float d = __fadd_rn(__fadd_rn(__fmul_rn(dx,dx), __fmul_rn(dy,dy)), __fmul_rn(dz,dz));
      float nd = fminf(dm[u], d);
      dm[u] = nd;
      lmax = fmaxf(lmax, nd);
    }
    // wave-wide exact max via DPP (valid in lane 63)
    float v = lmax;
#define DPPMAX(ctrl) { float tv_ = __int_as_float(__builtin_amdgcn_update_dpp( \
      __float_as_int(v), __float_as_int(v), ctrl, 0xF, 0xF, false)); v = fmaxf(v, tv_); }
    DPPMAX(0x121)  // row_ror:1
    DPPMAX(0x122)  // row_ror:2
    DPPMAX(0x124)  // row_ror:4
    DPPMAX(0x128)  // row_ror:8
    DPPMAX(0x142)  // row_bcast15
    DPPMAX(0x143)  // row_bcast31
#undef DPPMAX
    float winv = __int_as_float(__builtin_amdgcn_readlane(__float_as_int(v), 63));
    unsigned long long mask = __ballot(lmax == winv);
    int wl = __ffsll(mask) - 1;               // lowest matching lane in wave
    int par = it & 1;
    if(l == wl){
      int um = 7;
#pragma unroll
      for(int u=6;u>=0;u--) if(dm[u] == winv) um = u;   // lowest matching u
      bval[par][w] = winv;
      bidx[par][w] = t*8 + um;
    }
    __syncthreads();
    float bv = bval[par][0]; int bj = bidx[par][0];
#pragma unroll
    for(int ww=1; ww<4; ww++){
      float v2 = bval[par][ww];
      if(v2 > bv){ bv = v2; bj = bidx[par][ww]; }   // strict: ties keep lower wave = lower j
    }
    last = bj;
    if(t==0) fpsidx[b*1024 + it] = last;
  }
}

// ---------------- k_gather: final column gather into outputs ----------------
__global__ __launch_bounds__(256) void k_gather(const float* __restrict__ x,
    const float* __restrict__ y, const int* __restrict__ fpsidx, float* __restrict__ out)
{
  int i = blockIdx.x*256 + threadIdx.x;       // 524288 threads
  if(i < 12288){
    int b = i / 3072, rem = i - b*3072, c = rem >> 10, m = rem & 1023;
    int j = fpsidx[b*1024 + m];
    out[i] = x[(size_t)b*6144 + c*2048 + j];
  }
  {
    int b = i >> 17, rem = i & 131071, c = rem >> 10, m = rem & 1023;
    int j = fpsidx[b*1024 + m];
    out[12288 + i] = y[((size_t)(b*128 + c))*2048 + j];
  }
}

// ---------------- launcher ----------------
extern "C" void kernel_launch(void* const* d_in, const int* in_sizes, int n_in,
                              void* d_out, int out_size, void* d_ws, size_t ws_size,
                              hipStream_t stream) {
  (void)in_sizes; (void)n_in; (void)out_size; (void)ws_size;
  const float* x      = (const float*)d_in[0];
  const float* w_it   = (const float*)d_in[1];
  const float* b_it   = (const float*)d_in[2];
  const float* wl1    = (const float*)d_in[3];
  const float* gn1_g  = (const float*)d_in[4];
  const float* gn1_b  = (const float*)d_in[5];
  const float* wl2    = (const float*)d_in[6];
  const float* gn2_g  = (const float*)d_in[7];
  const float* gn2_b  = (const float*)d_in[8];
  const float* e1_n1g = (const float*)d_in[9];
  const float* e1_n1b = (const float*)d_in[10];
  const float* e1_qkv = (const float*)d_in[11];
  const float* e1_pw  = (const float*)d_in[12];
  const float* e1_pb  = (const float*)d_in[13];
  const float* e1_mw  = (const float*)d_in[14];
  const float* e1_mb  = (const float*)d_in[15];
  const float* e1_c1  = (const float*)d_in[16];
  const float* e1_c2  = (const float*)d_in[17];
  const float* e1_n2g = (const float*)d_in[18];
  const float* e1_n2b = (const float*)d_in[19];
  const float* e1_f1w = (const float*)d_in[20];
  const float* e1_f1b = (const float*)d_in[21];
  const float* e1_f2w = (const float*)d_in[22];
  const float* e1_f2b = (const float*)d_in[23];
  const float* e2_n1g = (const float*)d_in[24];
  const float* e2_n1b = (const float*)d_in[25];
  const float* e2_qkv = (const float*)d_in[26];
  const float* e2_pw  = (const float*)d_in[27];
  const float* e2_pb  = (const float*)d_in[28];
  const float* e2_n2g = (const float*)d_in[29];
  const float* e2_n2b = (const float*)d_in[30];
  const float* e2_f1w = (const float*)d_in[31];
  const float* e2_f1b = (const float*)d_in[32];
  const float* e2_f2w = (const float*)d_in[33];
  const float* e2_f2b = (const float*)d_in[34];

  float* p = (float*)d_ws;
  float* ft     = p; p += 262144;
  float* sq     = p; p += 8192;
  int*   knnidx = (int*)p; p += 131072;
  float* nx     = p; p += 24576;
  float* qkv1   = p; p += 73728;
  float* obuf1  = p; p += 24576;
  float* x1     = p; p += 24576;
  float* s1     = p; p += 1024;
  float* t1     = p; p += 1024;
  float* s2     = p; p += 512;
  float* t2     = p; p += 512;
  float* part1  = p; p += 32768;
  float* part2  = p; p += 32768;
  float* hmax   = p; p += 1048576;
  float* hmin   = p; p += 1048576;
  float* knnf   = p; p += 1048576;
  float* h1     = p; p += 1048576;
  float* ybuf   = p; p += 1048576;
  float* lnbuf  = p; p += 1048576;
  float* hbuf   = p; p += 2097152;
  float* qkvbuf = p; p += 3145728;
  float* obuf2  = p; p += 1048576;
  int*   fpsidx = (int*)p; p += 4096;
  float* out    = (float*)d_out;

  k_ft_sq<<<32,256,0,stream>>>(x, w_it, b_it, ft, sq);
  k_knn<<<2048,256,0,stream>>>(x, sq, knnidx);
  k_ln<<<12,256,0,stream>>>(x, e1_n1g, e1_n1b, nx);
  k_qkv1<<<1536,256,0,stream>>>(nx, e1_qkv, qkv1);
  k_attn1<<<32,256,0,stream>>>(qkv1, obuf1);
  k_proj1<<<512,256,0,stream>>>(nx, obuf1, e1_pw, e1_pb, x1);
  k_convknn<0><<<4096,256,0,stream>>>(ft, knnidx, wl1, wl2, nullptr, nullptr,
                                      part1, nullptr, nullptr, nullptr);
  k_gn1fin<<<1,256,0,stream>>>(part1, gn1_g, gn1_b, s1, t1);
  k_convknn<1><<<4096,256,0,stream>>>(ft, knnidx, wl1, wl2, s1, t1,
                                      part1, part2, hmax, hmin);
  k_gn2fin<<<1,256,0,stream>>>(part2, gn2_g, gn2_b, s2, t2);
  k_knnf<<<1024,256,0,stream>>>(hmax, hmin, s2, t2, knnf);
  // h1 = e1_c2 @ gelu(e1_c1 @ x1)   (per batch)
  k_gemm<0,1,0><<<dim3(32,2,4),256,0,stream>>>(e1_c2, nullptr, nullptr, x1, e1_c1,
                                               nullptr, nullptr, h1, 128, 2048, 512);
  // y = h1 + concat(h1,knnf) @ e1_mw^T + e1_mb
  k_gemm<1,0,2><<<dim3(32,8,1),256,0,stream>>>(h1, knnf, e1_mw, nullptr, nullptr,
                                               e1_mb, h1, ybuf, 512, 2048, 4096);
  // MLP 1
  k_ln<<<512,256,0,stream>>>(ybuf, e1_n2g, e1_n2b, lnbuf);
  k_gemm<0,0,1><<<dim3(64,8,1),256,0,stream>>>(lnbuf, nullptr, e1_f1w, nullptr, nullptr,
                                               e1_f1b, nullptr, hbuf, 512, 4096, 2048);
  k_gemm<0,0,2><<<dim3(32,8,1),256,0,stream>>>(hbuf, nullptr, e1_f2w, nullptr, nullptr,
                                               e1_f2b, ybuf, ybuf, 512, 2048, 4096);
  // attention 2
  k_ln<<<512,256,0,stream>>>(ybuf, e2_n1g, e2_n1b, lnbuf);
  k_gemm<0,0,0><<<dim3(96,8,1),256,0,stream>>>(lnbuf, nullptr, e2_qkv, nullptr, nullptr,
                                               nullptr, nullptr, qkvbuf, 512, 6144, 2048);
  k_attn2<<<32,256,0,stream>>>(qkvbuf, obuf2);
  k_gemm<0,0,2><<<dim3(32,8,1),256,0,stream>>>(obuf2, nullptr, e2_pw, nullptr, nullptr,
                                               e2_pb, ybuf, ybuf, 512, 2048, 2048);
  // MLP 2
  k_ln<<<512,256,0,stream>>>(ybuf, e2_n2g, e2_n2b, lnbuf);
  k_gemm<0,0,1><<<dim3(64,8,1),256,0,stream>>>(lnbuf, nullptr, e2_f1w, nullptr, nullptr,
                                               e2_f1b, nullptr, hbuf, 512, 4096, 2048);
  k_gemm<0,0,2><<<dim3(32,8,1),256,0,stream>>>(hbuf, nullptr, e2_f2w, nullptr, nullptr,
                                               e2_f2b, ybuf, ybuf, 512, 2048, 4096);
  // FPS + gather
  k_fps<<<4,256,0,stream>>>(x, fpsidx);
  k_gather<<<2048,256,0,stream>>>(x, ybuf, fpsidx, out);
}